// Round 5
// baseline (195.386 us; speedup 1.0000x reference)
//
#include <hip/hip_runtime.h>
#include <hip/hip_bf16.h>

// Problem constants
#define B_  64
#define N_  4096
#define F_  64
#define H1_ 128
#define H2_ 128

#define GRID_ 2048          // one 128-row tile per block, 4 waves x 32 rows

typedef __attribute__((ext_vector_type(8))) short bf16x8;   // 8 bf16 (4 VGPRs)
typedef __attribute__((ext_vector_type(4))) float f32x4;    // MFMA accumulator

// pack two f32 -> one u32 of 2 bf16 (RNE); compiler emits v_cvt_pk_bf16_f32
__device__ __forceinline__ unsigned int cvtpk(float lo, float hi) {
    __hip_bfloat162 h = __float22bfloat162_rn(make_float2(lo, hi));
    union { __hip_bfloat162 h; unsigned int u; } c; c.h = h; return c.u;
}

// ---------------------------------------------------------------------------
// Fused MLP -> exp(masked logits) -> per-batch sum.
// Block = 256 thr (4 waves); block tile = 128 rows; wave = 32 rows in 2x16
// substeps.  LDS layouts are UNPADDED [*][128] (row stride 256B == 0 mod 32
// banks) with XOR swizzle  byte ^= (row&7)<<4  => b128 reads land on
// slot (4ks+lg)^(row&7): perfectly balanced, zero bank conflicts.
// Layer 1 swapped operands: C1=mfma(W1^T, X^T) -> lane holds col=row(lr),
// rows h=lg*4+j; H1 round-trips a per-wave LDS slice (lgkmcnt only).
// Layer 2 standard: C2=mfma(H1, W2^T-from-LDS).
// ---------------------------------------------------------------------------
__global__ __launch_bounds__(256, 3) void mlp_kernel(
    const float* __restrict__ x,
    const int*   __restrict__ mask,
    const float* __restrict__ W1,    // [F=64][H1=128] f32
    const float* __restrict__ b1,
    const float* __restrict__ W2,    // [H1=128][H2=128] f32
    const float* __restrict__ b2,
    const float* __restrict__ W3,
    const float* __restrict__ b3,
    float* __restrict__ eout,        // exp(tns) per row
    float* __restrict__ sums)        // [B] batch exp-sums (pre-zeroed)
{
    __shared__ unsigned short W2s[128][128];    // [h2][h1], swizzled  (32 KB)
    __shared__ unsigned short H1s[4][16][128];  // per-wave, swizzled  (16 KB)
    __shared__ float b1s[128];                  // total ~49.7 KB -> 3 blk/CU

    const int t    = threadIdx.x;
    const int wave = t >> 6;
    const int lane = t & 63;
    const int lr   = lane & 15;
    const int lg   = lane >> 4;
    const int rb   = blockIdx.x * 128 + wave * 32;   // this wave's rows

    // ---- issue x loads for both substeps FIRST (longest latency) ----
    float4 xs[2][2][2];                   // [substep][ks][half]
    #pragma unroll
    for (int s = 0; s < 2; ++s)
        #pragma unroll
        for (int ks = 0; ks < 2; ++ks) {
            const float4* p = (const float4*)(x + (size_t)(rb + s * 16 + lr) * 64 + ks * 32 + lg * 8);
            xs[s][ks][0] = p[0];
            xs[s][ks][1] = p[1];
        }
    int4 mk[2];
    if (lr == 0) {
        mk[0] = *(const int4*)&mask[rb + lg * 4];
        mk[1] = *(const int4*)&mask[rb + 16 + lg * 4];
    }

    // ---- stage W2^T into LDS, swizzled: thread owns row h2=t>>1, half ----
    {
        const int h2   = t >> 1;
        const int half = (t & 1) << 6;
        const int swz  = (h2 & 7) << 4;
        #pragma unroll
        for (int g = 0; g < 8; ++g) {
            float v[8];
            #pragma unroll
            for (int i = 0; i < 8; ++i)
                v[i] = W2[(size_t)(half + g * 8 + i) * 128 + h2];   // coalesced across lanes
            uint4 u = make_uint4(cvtpk(v[0], v[1]), cvtpk(v[2], v[3]),
                                 cvtpk(v[4], v[5]), cvtpk(v[6], v[7]));
            char* bp = (char*)&W2s[h2][0] + (((half + g * 8) * 2) ^ swz);
            *(uint4*)bp = u;
        }
    }
    if (t < 32) *(float4*)&b1s[t * 4] = ((const float4*)b1)[t];

    // ---- W1 A-fragments into registers (16 frags = 64 VGPR) ----
    bf16x8 w1f[8][2];                     // [h-block][k-step]
    #pragma unroll
    for (int hb = 0; hb < 8; ++hb)
        #pragma unroll
        for (int ks = 0; ks < 2; ++ks) {
            float v[8];
            #pragma unroll
            for (int i = 0; i < 8; ++i)
                v[i] = W1[(size_t)(ks * 32 + lg * 8 + i) * 128 + hb * 16 + lr];
            union { uint4 u; bf16x8 b; } c;
            c.u = make_uint4(cvtpk(v[0], v[1]), cvtpk(v[2], v[3]),
                             cvtpk(v[4], v[5]), cvtpk(v[6], v[7]));
            w1f[hb][ks] = c.b;
        }
    // per-lane epilogue constants (col = hb*16 + lr)
    float b2v[8], w3v[8];
    #pragma unroll
    for (int hb = 0; hb < 8; ++hb) {
        b2v[hb] = b2[hb * 16 + lr];
        w3v[hb] = W3[hb * 16 + lr];
    }
    const float b3v = b3[0];
    __syncthreads();                      // the only block-wide barrier

    unsigned short (*H1w)[128] = H1s[wave];
    const int swzr = (lr & 7) << 4;       // byte XOR for row = lr
    float ssum = 0.0f;

    #pragma unroll
    for (int s = 0; s < 2; ++s) {
        // ---- pack x substep to bf16 B-fragments ----
        bf16x8 xb[2];
        #pragma unroll
        for (int ks = 0; ks < 2; ++ks) {
            float4 a = xs[s][ks][0], b = xs[s][ks][1];
            union { uint4 u; bf16x8 b; } c;
            c.u = make_uint4(cvtpk(a.x, a.y), cvtpk(a.z, a.w),
                             cvtpk(b.x, b.y), cvtpk(b.z, b.w));
            xb[ks] = c.b;
        }

        // ---- layer 1: C1[h=128][row=16], acc init = b1 ----
        f32x4 acc[8];
        #pragma unroll
        for (int hb = 0; hb < 8; ++hb)
            acc[hb] = *(const f32x4*)&b1s[hb * 16 + lg * 4];
        #pragma unroll
        for (int ks = 0; ks < 2; ++ks)
            #pragma unroll
            for (int hb = 0; hb < 8; ++hb)
                acc[hb] = __builtin_amdgcn_mfma_f32_16x16x32_bf16(w1f[hb][ks], xb[ks], acc[hb], 0, 0, 0);

        // ---- relu -> bf16 -> per-wave H1 slice (swizzled u64 writes) ----
        #pragma unroll
        for (int hb = 0; hb < 8; ++hb) {
            unsigned int u0 = cvtpk(fmaxf(acc[hb][0], 0.0f), fmaxf(acc[hb][1], 0.0f));
            unsigned int u1 = cvtpk(fmaxf(acc[hb][2], 0.0f), fmaxf(acc[hb][3], 0.0f));
            char* bp = (char*)&H1w[lr][0] + (((hb * 16 + lg * 4) * 2) ^ swzr);
            *(uint2*)bp = make_uint2(u0, u1);
        }
        asm volatile("s_waitcnt lgkmcnt(0)" ::: "memory");  // same-wave slice

        // ---- layer 2: C2[row=16][h2=128], acc init = b2 ----
        bf16x8 a2[4];
        #pragma unroll
        for (int ks = 0; ks < 4; ++ks) {
            const char* bp = (const char*)&H1w[lr][0] + (((ks * 32 + lg * 8) * 2) ^ swzr);
            a2[ks] = *(const bf16x8*)bp;
        }
        f32x4 c2[8];
        #pragma unroll
        for (int hb = 0; hb < 8; ++hb) {
            f32x4 ci = {b2v[hb], b2v[hb], b2v[hb], b2v[hb]};
            c2[hb] = ci;
        }
        #pragma unroll
        for (int ks = 0; ks < 4; ++ks)
            #pragma unroll
            for (int hb = 0; hb < 8; ++hb) {
                const char* bp = (const char*)&W2s[hb * 16 + lr][0] + (((ks * 32 + lg * 8) * 2) ^ swzr);
                bf16x8 bfrag = *(const bf16x8*)bp;
                c2[hb] = __builtin_amdgcn_mfma_f32_16x16x32_bf16(a2[ks], bfrag, c2[hb], 0, 0, 0);
            }

        // ---- layer 3 + mask + exp ----
        float p[4];
        #pragma unroll
        for (int j = 0; j < 4; ++j) {
            float sj = 0.0f;
            #pragma unroll
            for (int hb = 0; hb < 8; ++hb)
                sj += fmaxf(c2[hb][j], 0.0f) * w3v[hb];
            p[j] = sj;
        }
        #pragma unroll
        for (int m = 1; m < 16; m <<= 1)
            #pragma unroll
            for (int j = 0; j < 4; ++j)
                p[j] += __shfl_xor(p[j], m, 64);

        if (lr == 0) {                    // rows rb + s*16 + lg*4 .. +4
            int r0 = rb + s * 16 + lg * 4;
            float4 ev;
            ev.x = mk[s].x ? expf(p[0] + b3v) : 0.0f;
            ev.y = mk[s].y ? expf(p[1] + b3v) : 0.0f;
            ev.z = mk[s].z ? expf(p[2] + b3v) : 0.0f;
            ev.w = mk[s].w ? expf(p[3] + b3v) : 0.0f;
            *(float4*)&eout[r0] = ev;
            ssum += ev.x + ev.y + ev.z + ev.w;
        }
    }

    // ---- one batch-sum atomic per wave (batch = blockIdx/32) ----
    ssum += __shfl_xor(ssum, 16, 64);
    ssum += __shfl_xor(ssum, 32, 64);
    if (lane == 0) atomicAdd(&sums[blockIdx.x >> 5], ssum);
}

// ---------------------------------------------------------------------------
// out = e / sums[batch]
// ---------------------------------------------------------------------------
__global__ __launch_bounds__(256) void norm_kernel(
    const float* __restrict__ e, const float* __restrict__ sums,
    float* __restrict__ out)
{
    int i4 = blockIdx.x * 256 + threadIdx.x;       // 65536 float4s
    float4 v = ((const float4*)e)[i4];
    float inv = 1.0f / sums[i4 >> 10];             // 1024 float4 per batch
    v.x *= inv; v.y *= inv; v.z *= inv; v.w *= inv;
    ((float4*)out)[i4] = v;
}

// ---------------------------------------------------------------------------
extern "C" void kernel_launch(void* const* d_in, const int* in_sizes, int n_in,
                              void* d_out, int out_size, void* d_ws, size_t ws_size,
                              hipStream_t stream)
{
    const float* x    = (const float*)d_in[0];
    const int*   mask = (const int*)d_in[1];
    const float* W1   = (const float*)d_in[2];
    const float* b1   = (const float*)d_in[3];
    const float* W2   = (const float*)d_in[4];
    const float* b2   = (const float*)d_in[5];
    const float* W3   = (const float*)d_in[6];
    const float* b3   = (const float*)d_in[7];
    float* out = (float*)d_out;

    float* sums = (float*)d_ws;                          // 64 floats
    float* eout = (float*)((char*)d_ws + 1024);          // 1 MB

    hipMemsetAsync(sums, 0, B_ * sizeof(float), stream);
    mlp_kernel<<<GRID_, 256, 0, stream>>>(x, mask, W1, b1, W2, b2, W3, b3, eout, sums);
    norm_kernel<<<(B_ * N_ / 4) / 256, 256, 0, stream>>>(eout, sums, out);
}

// Round 6
// 135.225 us; speedup vs baseline: 1.4449x; 1.4449x over previous
//
#include <hip/hip_runtime.h>
#include <hip/hip_bf16.h>

// Problem constants
#define B_  64
#define N_  4096
#define F_  64
#define H1_ 128
#define H2_ 128

#define GRID_   512         // persistent, 2 blocks/CU
#define MACROS_ 2           // 2 macro-iters x 256 rows per block = 512 rows

typedef __attribute__((ext_vector_type(8))) short bf16x8;   // 8 bf16 (4 VGPRs)
typedef __attribute__((ext_vector_type(4))) float f32x4;    // MFMA accumulator

// pack two f32 -> u32 of 2 bf16 (RNE); compiler emits v_cvt_pk_bf16_f32
__device__ __forceinline__ unsigned int cvtpk(float lo, float hi) {
    __hip_bfloat162 h = __float22bfloat162_rn(make_float2(lo, hi));
    union { __hip_bfloat162 h; unsigned int u; } c; c.h = h; return c.u;
}

// ---------------------------------------------------------------------------
// Fused MLP -> exp(masked logits) -> per-batch sum.
// Block = 256 thr (4 waves). Per macro-iter each wave owns 64 rows:
//   4x 16-row L1 rounds (W1 in regs, swapped-operand MFMA, H1 round-trip
//   through a double-buffered per-wave swizzled LDS slice, a2[4][4] in regs)
//   then ONE W2 pass (hb-outer, c2[4] only) -> W2 LDS traffic = 32 b128
//   per 64 rows per wave (half of R4).
// LDS unpadded [*][128] + XOR swizzle byte^=(row&7)<<4 => conflict-free b128.
// ---------------------------------------------------------------------------
__global__ __launch_bounds__(256, 2) void mlp_kernel(
    const float* __restrict__ x,
    const int*   __restrict__ mask,
    const float* __restrict__ W1,    // [F=64][H1=128] f32
    const float* __restrict__ b1,
    const float* __restrict__ W2,    // [H1=128][H2=128] f32
    const float* __restrict__ b2,
    const float* __restrict__ W3,
    const float* __restrict__ b3,
    float* __restrict__ eout,        // exp(tns) per row
    float* __restrict__ sums)        // [B] batch exp-sums (pre-zeroed)
{
    __shared__ unsigned short W2s[128][128];       // [h2][h1] swizzled (32 KB)
    __shared__ unsigned short H1s[4][2][16][128];  // per-wave dbuf     (32 KB)
    __shared__ float b1s[128];                     // total 64.5 KB -> 2 blk/CU

    const int t    = threadIdx.x;
    const int wave = t >> 6;
    const int lane = t & 63;
    const int lr   = lane & 15;
    const int lg   = lane >> 4;

    // ---- stage W2^T into LDS, swizzled b128 writes (one-time) ----
    {
        const int h2   = t >> 1;
        const int half = (t & 1) << 6;
        const int swz  = (h2 & 7) << 4;
        #pragma unroll
        for (int g = 0; g < 8; ++g) {
            float v[8];
            #pragma unroll
            for (int i = 0; i < 8; ++i)
                v[i] = W2[(size_t)(half + g * 8 + i) * 128 + h2];
            uint4 u = make_uint4(cvtpk(v[0], v[1]), cvtpk(v[2], v[3]),
                                 cvtpk(v[4], v[5]), cvtpk(v[6], v[7]));
            char* bp = (char*)&W2s[h2][0] + (((half + g * 8) * 2) ^ swz);
            *(uint4*)bp = u;
        }
    }
    if (t < 32) *(float4*)&b1s[t * 4] = ((const float4*)b1)[t];

    // ---- W1 A-fragments into registers (16 frags = 64 VGPR) ----
    bf16x8 w1f[8][2];                     // [h-block][k-step]
    #pragma unroll
    for (int hb = 0; hb < 8; ++hb)
        #pragma unroll
        for (int ks = 0; ks < 2; ++ks) {
            float v[8];
            #pragma unroll
            for (int i = 0; i < 8; ++i)
                v[i] = W1[(size_t)(ks * 32 + lg * 8 + i) * 128 + hb * 16 + lr];
            union { uint4 u; bf16x8 b; } c;
            c.u = make_uint4(cvtpk(v[0], v[1]), cvtpk(v[2], v[3]),
                             cvtpk(v[4], v[5]), cvtpk(v[6], v[7]));
            w1f[hb][ks] = c.b;
        }
    float b2v[8], w3v[8];                 // epilogue constants (col hb*16+lr)
    #pragma unroll
    for (int hb = 0; hb < 8; ++hb) {
        b2v[hb] = b2[hb * 16 + lr];
        w3v[hb] = W3[hb * 16 + lr];
    }
    const float b3v = b3[0];
    __syncthreads();                      // the only block-wide barrier

    const int swzr = (lr & 7) << 4;       // byte XOR for row = lr
    float ssum = 0.0f;

    #define LOADX_(dst, row16)                                                  \
        do {                                                                    \
            _Pragma("unroll")                                                   \
            for (int ks_ = 0; ks_ < 2; ++ks_) {                                 \
                const float4* p_ = (const float4*)(x +                          \
                    (size_t)((row16) + lr) * 64 + ks_ * 32 + lg * 8);           \
                dst[ks_][0] = p_[0];                                            \
                dst[ks_][1] = p_[1];                                            \
            }                                                                   \
        } while (0)

    for (int m = 0; m < MACROS_; ++m) {
        const int rb = blockIdx.x * 512 + m * 256 + wave * 64;  // wave's 64 rows

        // mask for epilogue rows, issued early
        int4 mk[4];
        if (lr == 0) {
            #pragma unroll
            for (int mb = 0; mb < 4; ++mb)
                mk[mb] = *(const int4*)&mask[rb + mb * 16 + lg * 4];
        }

        bf16x8 a2[4][4];                  // [mb][ks] layer-2 A-frags (64 VGPR)
        float4 xf[2][2][2];               // x double buffer [buf][ks][half]
        LOADX_(xf[0], rb);

        // ---- 4x 16-row L1 rounds ----
        #pragma unroll
        for (int r = 0; r < 4; ++r) {
            const int cur = r & 1;
            if (r < 3) LOADX_(xf[cur ^ 1], rb + (r + 1) * 16);

            bf16x8 xb[2];
            #pragma unroll
            for (int ks = 0; ks < 2; ++ks) {
                float4 a = xf[cur][ks][0], b = xf[cur][ks][1];
                union { uint4 u; bf16x8 b; } c;
                c.u = make_uint4(cvtpk(a.x, a.y), cvtpk(a.z, a.w),
                                 cvtpk(b.x, b.y), cvtpk(b.z, b.w));
                xb[ks] = c.b;
            }

            f32x4 acc[8];
            #pragma unroll
            for (int hb = 0; hb < 8; ++hb)
                acc[hb] = *(const f32x4*)&b1s[hb * 16 + lg * 4];
            #pragma unroll
            for (int ks = 0; ks < 2; ++ks)
                #pragma unroll
                for (int hb = 0; hb < 8; ++hb)
                    acc[hb] = __builtin_amdgcn_mfma_f32_16x16x32_bf16(
                                  w1f[hb][ks], xb[ks], acc[hb], 0, 0, 0);

            // relu -> bf16 -> per-wave H1 slice (swizzled b64 writes)
            unsigned short (*H1w)[128] = H1s[wave][cur];
            #pragma unroll
            for (int hb = 0; hb < 8; ++hb) {
                unsigned int u0 = cvtpk(fmaxf(acc[hb][0], 0.0f), fmaxf(acc[hb][1], 0.0f));
                unsigned int u1 = cvtpk(fmaxf(acc[hb][2], 0.0f), fmaxf(acc[hb][3], 0.0f));
                char* bp = (char*)&H1w[lr][0] + (((hb * 16 + lg * 4) * 2) ^ swzr);
                *(uint2*)bp = make_uint2(u0, u1);
            }
            asm volatile("s_waitcnt lgkmcnt(0)" ::: "memory");  // same-wave slice

            #pragma unroll
            for (int ks = 0; ks < 4; ++ks) {
                const char* bp = (const char*)&H1w[lr][0] + (((ks * 32 + lg * 8) * 2) ^ swzr);
                a2[r][ks] = *(const bf16x8*)bp;
            }
        }

        // ---- W2 pass: 64 rows, hb-outer / ks-inner, c2[4] live only ----
        float p[4][4];
        #pragma unroll
        for (int mb = 0; mb < 4; ++mb)
            #pragma unroll
            for (int j = 0; j < 4; ++j) p[mb][j] = 0.0f;

        #pragma unroll
        for (int hb = 0; hb < 8; ++hb) {
            f32x4 c2[4];
            #pragma unroll
            for (int mb = 0; mb < 4; ++mb) {
                f32x4 ci = {b2v[hb], b2v[hb], b2v[hb], b2v[hb]};
                c2[mb] = ci;
            }
            #pragma unroll
            for (int ks = 0; ks < 4; ++ks) {
                const char* bp = (const char*)&W2s[hb * 16 + lr][0]
                               + (((ks * 32 + lg * 8) * 2) ^ swzr);
                bf16x8 bfrag = *(const bf16x8*)bp;
                #pragma unroll
                for (int mb = 0; mb < 4; ++mb)
                    c2[mb] = __builtin_amdgcn_mfma_f32_16x16x32_bf16(
                                 a2[mb][ks], bfrag, c2[mb], 0, 0, 0);
            }
            #pragma unroll
            for (int mb = 0; mb < 4; ++mb)
                #pragma unroll
                for (int j = 0; j < 4; ++j)
                    p[mb][j] += fmaxf(c2[mb][j], 0.0f) * w3v[hb];
        }

        // ---- reduce over the 16 lr lanes (h2 dimension) ----
        #pragma unroll
        for (int msk = 1; msk < 16; msk <<= 1)
            #pragma unroll
            for (int mb = 0; mb < 4; ++mb)
                #pragma unroll
                for (int j = 0; j < 4; ++j)
                    p[mb][j] += __shfl_xor(p[mb][j], msk, 64);

        // ---- mask + exp + store (lr==0 lanes own rows rb+mb*16+lg*4..+3) ----
        if (lr == 0) {
            #pragma unroll
            for (int mb = 0; mb < 4; ++mb) {
                int r0 = rb + mb * 16 + lg * 4;
                float4 ev;
                ev.x = mk[mb].x ? expf(p[mb][0] + b3v) : 0.0f;
                ev.y = mk[mb].y ? expf(p[mb][1] + b3v) : 0.0f;
                ev.z = mk[mb].z ? expf(p[mb][2] + b3v) : 0.0f;
                ev.w = mk[mb].w ? expf(p[mb][3] + b3v) : 0.0f;
                *(float4*)&eout[r0] = ev;
                ssum += ev.x + ev.y + ev.z + ev.w;
            }
        }
    }
    #undef LOADX_

    // ---- one batch-sum atomic per wave (block rows lie in one batch) ----
    ssum += __shfl_xor(ssum, 16, 64);
    ssum += __shfl_xor(ssum, 32, 64);
    if (lane == 0) atomicAdd(&sums[blockIdx.x >> 3], ssum);
}

// ---------------------------------------------------------------------------
// out = e / sums[batch]
// ---------------------------------------------------------------------------
__global__ __launch_bounds__(256) void norm_kernel(
    const float* __restrict__ e, const float* __restrict__ sums,
    float* __restrict__ out)
{
    int i4 = blockIdx.x * 256 + threadIdx.x;       // 65536 float4s
    float4 v = ((const float4*)e)[i4];
    float inv = 1.0f / sums[i4 >> 10];             // 1024 float4 per batch
    v.x *= inv; v.y *= inv; v.z *= inv; v.w *= inv;
    ((float4*)out)[i4] = v;
}

// ---------------------------------------------------------------------------
extern "C" void kernel_launch(void* const* d_in, const int* in_sizes, int n_in,
                              void* d_out, int out_size, void* d_ws, size_t ws_size,
                              hipStream_t stream)
{
    const float* x    = (const float*)d_in[0];
    const int*   mask = (const int*)d_in[1];
    const float* W1   = (const float*)d_in[2];
    const float* b1   = (const float*)d_in[3];
    const float* W2   = (const float*)d_in[4];
    const float* b2   = (const float*)d_in[5];
    const float* W3   = (const float*)d_in[6];
    const float* b3   = (const float*)d_in[7];
    float* out = (float*)d_out;

    float* sums = (float*)d_ws;                          // 64 floats
    float* eout = (float*)((char*)d_ws + 1024);          // 1 MB

    hipMemsetAsync(sums, 0, B_ * sizeof(float), stream);
    mlp_kernel<<<GRID_, 256, 0, stream>>>(x, mask, W1, b1, W2, b2, W3, b3, eout, sums);
    norm_kernel<<<(B_ * N_ / 4) / 256, 256, 0, stream>>>(eout, sums, out);
}